// Round 17
// baseline (1822.961 us; speedup 1.0000x reference)
//
#include <hip/hip_runtime.h>
#include <math.h>

#define TT 2048
#define UU 64
#define BB 256
#define NTHR 128        // 2 waves: wave0 = producer (ALL gates, ALL k), wave1 = consumer
#define CH 16           // timesteps per chunk (one barrier per chunk)
#define NCH (TT / CH)   // 128 chunks -> 129 barriers total (vs 2050 in r16)
#define NSLOT 32        // h ring slots (2 chunks deep)

typedef float v2f __attribute__((ext_vector_type(2)));
typedef float v4f __attribute__((ext_vector_type(4)));

// Fast activations on v_exp_f32 / v_rcp_f32 (~1e-7 abs err; threshold 3.45e-6;
// validated across rounds 0-16).
__device__ __forceinline__ float frcp(float x) { return __builtin_amdgcn_rcpf(x); }
__device__ __forceinline__ float fsigmoid(float x) { return frcp(1.0f + __expf(-x)); }
__device__ __forceinline__ float ftanh(float x) { return 1.0f - 2.0f * frcp(1.0f + __expf(2.0f * x)); }

// VOP3P op_sel splat-FMA (r10-validated). r12 ISA fact: VOP3P cannot source
// AGPRs -- AGPR-held weights are moved with v_accvgpr_read_b32 (2cy VALU).
__device__ __forceinline__ void pkfma_ll(v2f& a, v2f h, v2f w) {
    asm("v_pk_fma_f32 %0, %1, %2, %0 op_sel:[0,0,0] op_sel_hi:[0,1,1]"
        : "+v"(a) : "v"(h), "v"(w));
}
__device__ __forceinline__ void pkfma_hh(v2f& a, v2f h, v2f w) {
    asm("v_pk_fma_f32 %0, %1, %2, %0 op_sel:[1,0,0] op_sel_hi:[1,1,1]"
        : "+v"(a) : "v"(h), "v"(w));
}
// volatile: LICM must NOT hoist these (would re-create VGPR pressure)
#define RDA(d, s) asm volatile("v_accvgpr_read_b32 %0, %1" : "=v"(d) : "a"(s));

// R14+R16 POST-MORTEM: AGPR read-backs are FREE in the 3-wave structure
// (VGPR-resident 993us == AGPR-copies 999us) -> they hide in stall windows.
// The dominant remaining chain segment is the per-step barrier + cross-wave
// z exchange (~400-500cy), which exists only because layer 0 spans 2 waves.
// THIS ROUND: ONE producer wave, all 4 gates in-lane (z never leaves the
// lane), ZERO per-step barriers (consumer syncs via r7's proven 16-step
// chunk protocol). r7's 2460cy failure is explained by its 44 LDS-streamed
// weight reads (~30cy exposed each); here the overflow weights live in an
// AGPR stash read back with v_accvgpr_read (2cy, volatile, per-iteration).
// 32 v4f AGPR blockers (r14-proven) fill the AGPR file so the RA cannot
// silently re-stash the VGPR half.
// Per step: 16 uniform b128 ring reads + 128 pkfma + 128 accvgpr_read
// (8 chains x 16 deep) -> z in-lane -> act -> ring b32 write. Barrier only
// every CH steps. Wave 1: r7's consumer verbatim (shuffle reduce + L1 LSTM
// + dense, coalesced flush per 64). Both waves: exactly 1 + NCH barriers.
__global__
__attribute__((amdgpu_flat_work_group_size(NTHR, NTHR)))
__attribute__((amdgpu_waves_per_eu(1, 1)))
void lstm_ts_kernel(
    const float* __restrict__ x, const float* __restrict__ W0,
    const float* __restrict__ b0, const float* __restrict__ W1,
    const float* __restrict__ b1, const float* __restrict__ Wd,
    const float* __restrict__ bd, float* __restrict__ out)
{
    __shared__ __align__(16) float xbuf[TT];          // 8 KB
    __shared__ __align__(16) float ring[NSLOT][UU];   // plain-h ring, 8 KB
    __shared__ float red[2];

    const int tid = threadIdx.x;
    const int wid = tid >> 6;
    const int u = tid & 63;
    const int b = blockIdx.x;
    const float* xrow = x + b * TT;
    float* outrow = out + b * TT;

    // ---- prologue: stage x, sum of squares over T (both waves) ----
    float ss = 0.f;
    for (int i = tid; i < TT; i += NTHR) {
        float v = xrow[i];
        xbuf[i] = v;
        ss += v * v;
    }
    #pragma unroll
    for (int m = 1; m < 64; m <<= 1) ss += __shfl_xor(ss, m, 64);
    if (u == 0) red[wid] = ss;
    if (tid < UU) ring[NSLOT - 1][tid] = 0.f;  // h_{-1}=0 (iter 0 reads slot 31)
    __syncthreads();  // B0

    if (wid == 0) {
        // ========== PRODUCER: layer-0 LSTM, one wave, all 4 gates ==========
        const float sq = red[0] + red[1];
        const float scale = 1.0f / sqrtf(fmaxf(sq, 1e-12f));  // precise, once

        // VGPR half, k=0..31: WIk=(Wi[k][u],Wj[k][u]), WFk=(Wf[k][u],Wo[k][u])
        #define DECLWV(k) v2f WI##k, WF##k; { \
            const float* r_ = W0 + (1 + (k)) * 256; \
            WI##k.x = r_[u];       WI##k.y = r_[64 + u]; \
            WF##k.x = r_[128 + u]; WF##k.y = r_[192 + u]; } \
            asm volatile("" : "+v"(WI##k)); asm volatile("" : "+v"(WF##k));
        DECLWV(0)  DECLWV(1)  DECLWV(2)  DECLWV(3)  DECLWV(4)  DECLWV(5)
        DECLWV(6)  DECLWV(7)  DECLWV(8)  DECLWV(9)  DECLWV(10) DECLWV(11)
        DECLWV(12) DECLWV(13) DECLWV(14) DECLWV(15) DECLWV(16) DECLWV(17)
        DECLWV(18) DECLWV(19) DECLWV(20) DECLWV(21) DECLWV(22) DECLWV(23)
        DECLWV(24) DECLWV(25) DECLWV(26) DECLWV(27) DECLWV(28) DECLWV(29)
        DECLWV(30) DECLWV(31)
        #undef DECLWV

        // AGPR stash, k=32..63: 4 scalars per k = 128 AGPRs
        #define DECLWA(k) float AI##k, AJ##k, AF##k, AO##k; { \
            const float* r_ = W0 + (1 + (k)) * 256; \
            AI##k = r_[u]; AJ##k = r_[64 + u]; \
            AF##k = r_[128 + u]; AO##k = r_[192 + u]; } \
            asm volatile("" : "+a"(AI##k)); asm volatile("" : "+a"(AJ##k)); \
            asm volatile("" : "+a"(AF##k)); asm volatile("" : "+a"(AO##k));
        DECLWA(32) DECLWA(33) DECLWA(34) DECLWA(35) DECLWA(36) DECLWA(37)
        DECLWA(38) DECLWA(39) DECLWA(40) DECLWA(41) DECLWA(42) DECLWA(43)
        DECLWA(44) DECLWA(45) DECLWA(46) DECLWA(47) DECLWA(48) DECLWA(49)
        DECLWA(50) DECLWA(51) DECLWA(52) DECLWA(53) DECLWA(54) DECLWA(55)
        DECLWA(56) DECLWA(57) DECLWA(58) DECLWA(59) DECLWA(60) DECLWA(61)
        DECLWA(62) DECLWA(63)
        #undef DECLWA

        // AGPR blockers: 32 v4f = 128 AGPRs -> AGPR file full (128 stash+128)
        #define DECLB(k) v4f BL##k = {0.f, 0.f, 0.f, 0.f}; \
            asm volatile("" : "+a"(BL##k));
        DECLB(0)  DECLB(1)  DECLB(2)  DECLB(3)  DECLB(4)  DECLB(5)  DECLB(6)  DECLB(7)
        DECLB(8)  DECLB(9)  DECLB(10) DECLB(11) DECLB(12) DECLB(13) DECLB(14) DECLB(15)
        DECLB(16) DECLB(17) DECLB(18) DECLB(19) DECLB(20) DECLB(21) DECLB(22) DECLB(23)
        DECLB(24) DECLB(25) DECLB(26) DECLB(27) DECLB(28) DECLB(29) DECLB(30) DECLB(31)
        #undef DECLB

        const float wxi = W0[u] * scale,       wxj = W0[64 + u] * scale;
        const float wxf = W0[128 + u] * scale, wxo = W0[192 + u] * scale;
        const float bci = b0[u],       bcj = b0[64 + u];
        const float bcf = b0[128 + u], bco = b0[192 + u];

        float c0 = 0.f;

        for (int t = 0; t < TT; ++t) {
            // in-loop pins: blockers stay in AGPRs, weights stay in VGPRs
            #define PINB(k) asm volatile("" : "+a"(BL##k));
            PINB(0)  PINB(1)  PINB(2)  PINB(3)  PINB(4)  PINB(5)  PINB(6)  PINB(7)
            PINB(8)  PINB(9)  PINB(10) PINB(11) PINB(12) PINB(13) PINB(14) PINB(15)
            PINB(16) PINB(17) PINB(18) PINB(19) PINB(20) PINB(21) PINB(22) PINB(23)
            PINB(24) PINB(25) PINB(26) PINB(27) PINB(28) PINB(29) PINB(30) PINB(31)
            #undef PINB

            const float xr = xbuf[t];                          // uniform
            const float* hs = ring[(t + NSLOT - 1) & (NSLOT - 1)];

            // 8 chains x 16 deep; x/bias folded into chain 0
            v2f ai0, ai1 = 0.f, ai2 = 0.f, ai3 = 0.f;
            v2f af0, af1 = 0.f, af2 = 0.f, af3 = 0.f;
            ai0.x = fmaf(xr, wxi, bci); ai0.y = fmaf(xr, wxj, bcj);
            af0.x = fmaf(xr, wxf, bcf); af0.y = fmaf(xr, wxo, bco);

            // VGPR half: one uniform b128 = h_{4m..4m+3} -> 8 op_sel pkfma
            #define MACV(m, Wa, Wb, Wc, Wd_, Ea, Eb, Ec, Ed) { \
                v4f hv_ = *(const v4f*)(hs + 4 * (m)); \
                v2f h01_ = __builtin_shufflevector(hv_, hv_, 0, 1); \
                v2f h23_ = __builtin_shufflevector(hv_, hv_, 2, 3); \
                pkfma_ll(ai0, h01_, Wa); pkfma_hh(ai1, h01_, Wb); \
                pkfma_ll(ai2, h23_, Wc); pkfma_hh(ai3, h23_, Wd_); \
                pkfma_ll(af0, h01_, Ea); pkfma_hh(af1, h01_, Eb); \
                pkfma_ll(af2, h23_, Ec); pkfma_hh(af3, h23_, Ed); \
            }
            MACV(0, WI0,  WI1,  WI2,  WI3,  WF0,  WF1,  WF2,  WF3)
            MACV(1, WI4,  WI5,  WI6,  WI7,  WF4,  WF5,  WF6,  WF7)
            MACV(2, WI8,  WI9,  WI10, WI11, WF8,  WF9,  WF10, WF11)
            MACV(3, WI12, WI13, WI14, WI15, WF12, WF13, WF14, WF15)
            MACV(4, WI16, WI17, WI18, WI19, WF16, WF17, WF18, WF19)
            MACV(5, WI20, WI21, WI22, WI23, WF20, WF21, WF22, WF23)
            MACV(6, WI24, WI25, WI26, WI27, WF24, WF25, WF26, WF27)
            MACV(7, WI28, WI29, WI30, WI31, WF28, WF29, WF30, WF31)
            #undef MACV

            // AGPR half: 16 accvgpr_read (2cy each) + 8 pkfma per m
            #define MACA(m, k0, k1, k2, k3) { \
                v2f wa_, wb_, wc_, wd_, ea_, eb_, ec_, ed_; \
                RDA(wa_.x, AI##k0) RDA(wa_.y, AJ##k0) \
                RDA(wb_.x, AI##k1) RDA(wb_.y, AJ##k1) \
                RDA(wc_.x, AI##k2) RDA(wc_.y, AJ##k2) \
                RDA(wd_.x, AI##k3) RDA(wd_.y, AJ##k3) \
                RDA(ea_.x, AF##k0) RDA(ea_.y, AO##k0) \
                RDA(eb_.x, AF##k1) RDA(eb_.y, AO##k1) \
                RDA(ec_.x, AF##k2) RDA(ec_.y, AO##k2) \
                RDA(ed_.x, AF##k3) RDA(ed_.y, AO##k3) \
                v4f hv_ = *(const v4f*)(hs + 4 * (m)); \
                v2f h01_ = __builtin_shufflevector(hv_, hv_, 0, 1); \
                v2f h23_ = __builtin_shufflevector(hv_, hv_, 2, 3); \
                pkfma_ll(ai0, h01_, wa_); pkfma_hh(ai1, h01_, wb_); \
                pkfma_ll(ai2, h23_, wc_); pkfma_hh(ai3, h23_, wd_); \
                pkfma_ll(af0, h01_, ea_); pkfma_hh(af1, h01_, eb_); \
                pkfma_ll(af2, h23_, ec_); pkfma_hh(af3, h23_, ed_); \
            }
            MACA(8,  32, 33, 34, 35)
            MACA(9,  36, 37, 38, 39)
            MACA(10, 40, 41, 42, 43)
            MACA(11, 44, 45, 46, 47)
            MACA(12, 48, 49, 50, 51)
            MACA(13, 52, 53, 54, 55)
            MACA(14, 56, 57, 58, 59)
            MACA(15, 60, 61, 62, 63)
            #undef MACA

            const v2f zij = (ai0 + ai1) + (ai2 + ai3);
            const v2f zfo = (af0 + af1) + (af2 + af3);

            // ---- unit update: z never left the lane ----
            c0 = fsigmoid(zfo.x + 1.0f) * c0 + fsigmoid(zij.x) * ftanh(zij.y);
            const float h = fsigmoid(zfo.y) * ftanh(c0);

            ring[t & (NSLOT - 1)][u] = h;   // plain-h ring, b32 write

            if ((t & (CH - 1)) == (CH - 1)) __syncthreads();  // 1 per 16 steps
        }
    } else {
        // ================= CONSUMER: layer 1 + dense + store =================
        const float w1v0 = W1[u * 4 + 0], w1v1 = W1[u * 4 + 1];
        const float w1v2 = W1[u * 4 + 2], w1v3 = W1[u * 4 + 3];
        const float w1h0 = W1[256], w1h1 = W1[257], w1h2 = W1[258], w1h3 = W1[259];
        const float b10 = b1[0], b11 = b1[1], b12 = b1[2], b13 = b1[3];
        const float wd = Wd[0], bdv = bd[0];

        float c1 = 0.f, h1 = 0.f, oval = 0.f;

        // r7-proven chunk protocol: after barrier k2+1, slots of chunk k2 are
        // complete; producer overwrites them only after barrier k2+2.
        for (int k2 = 0; k2 < NCH; ++k2) {
            __syncthreads();  // chunk k2 is now fully in the ring
            const int sbase = k2 * CH;
            for (int si = 0; si < CH; ++si) {
                const int s = sbase + si;
                const float hu = ring[s & (NSLOT - 1)][u];  // 4B stride: free
                float p0 = hu * w1v0, p1 = hu * w1v1, p2 = hu * w1v2, p3 = hu * w1v3;
                #pragma unroll
                for (int m = 1; m < 64; m <<= 1) {
                    p0 += __shfl_xor(p0, m, 64);
                    p1 += __shfl_xor(p1, m, 64);
                    p2 += __shfl_xor(p2, m, 64);
                    p3 += __shfl_xor(p3, m, 64);
                }
                const float z1i = p0 + fmaf(h1, w1h0, b10);
                const float z1j = p1 + fmaf(h1, w1h1, b11);
                const float z1f = p2 + fmaf(h1, w1h2, b12);
                const float z1o = p3 + fmaf(h1, w1h3, b13);
                c1 = fsigmoid(z1f + 1.0f) * c1 + fsigmoid(z1i) * ftanh(z1j);
                h1 = fsigmoid(z1o) * ftanh(c1);
                const float ov = fmaf(h1, wd, bdv);
                if ((s & 63) == u) oval = ov;
                if ((s & 63) == 63) outrow[(s & ~63) + u] = oval;
            }
        }
    }
}

extern "C" void kernel_launch(void* const* d_in, const int* in_sizes, int n_in,
                              void* d_out, int out_size, void* d_ws, size_t ws_size,
                              hipStream_t stream) {
    const float* x  = (const float*)d_in[0];
    const float* W0 = (const float*)d_in[1];
    const float* b0 = (const float*)d_in[2];
    const float* W1 = (const float*)d_in[3];
    const float* b1 = (const float*)d_in[4];
    const float* Wd = (const float*)d_in[5];
    const float* bd = (const float*)d_in[6];
    float* out = (float*)d_out;
    lstm_ts_kernel<<<BB, NTHR, 0, stream>>>(x, W0, b0, W1, b1, Wd, bd, out);
}

// Round 18
// 1083.478 us; speedup vs baseline: 1.6825x; 1.6825x over previous
//
#include <hip/hip_runtime.h>
#include <math.h>

#define TT 2048
#define UU 64
#define BB 256
#define NTHR 192   // 3 waves: wave0 = k:0..31, wave1 = k:32..63 (producers), wave2 = consumer
#define CH 16      // consumer chunk size (one 3-wave barrier per chunk)
#define NCH (TT / CH)
#define NSLOT 32   // h ring slots (2 chunks deep)

typedef float v2f __attribute__((ext_vector_type(2)));
typedef float v4f __attribute__((ext_vector_type(4)));

// Fast activations on v_exp_f32 / v_rcp_f32 (~1e-7 abs err; threshold 3.45e-6;
// validated across rounds 0-17).
__device__ __forceinline__ float frcp(float x) { return __builtin_amdgcn_rcpf(x); }
__device__ __forceinline__ float fsigmoid(float x) { return frcp(1.0f + __expf(-x)); }
__device__ __forceinline__ float ftanh(float x) { return 1.0f - 2.0f * frcp(1.0f + __expf(2.0f * x)); }

// VOP3P op_sel splat-FMA (r10-validated): both result halves consume the SAME
// 32-bit half of h -- no (h,h) splat is ever materialized.
__device__ __forceinline__ void pkfma_ll(v2f& a, v2f h, v2f w) {
    asm("v_pk_fma_f32 %0, %1, %2, %0 op_sel:[0,0,0] op_sel_hi:[0,1,1]"
        : "+v"(a) : "v"(h), "v"(w));
}
__device__ __forceinline__ void pkfma_hh(v2f& a, v2f h, v2f w) {
    asm("v_pk_fma_f32 %0, %1, %2, %0 op_sel:[1,0,0] op_sel_hi:[1,1,1]"
        : "+v"(a) : "v"(h), "v"(w));
}

// ROUND-17 POST-MORTEM: single-wave = 2100cy/step (nothing hides latency);
// 2-producer K-split (r16, 959us) stands. r16's residual gap vs the ~550cy
// producer chain = (a) the CONSUMER's 6-level shfl reduce (~400cy) sharing
// the per-step barrier interval + (b) 3-wave barrier drain overhead.
// THIS ROUND cuts both without touching the proven MAC:
//  (1) consumer decoupled to the r7/r17-proven 16-step chunk protocol (its
//      reduce leaves the per-step critical path; 129 barriers total);
//  (2) producer z-exchange synced by an LDS FLAG HANDSHAKE per step:
//      write zpart -> s_waitcnt lgkmcnt(0) -> write flag[wid]=t+1 ->
//      poll flag[1-wid] >= t+1 (uniform broadcast read, ~1 poll).
//      Partner is bounded <=1 step ahead (its t+1 poll needs my flag t+2,
//      written after my step-t partner read) -> zpart t&1 dbuf race-free.
// Producer arithmetic bit-identical to r16; consumer identical to r17.
__global__
__attribute__((amdgpu_flat_work_group_size(NTHR, NTHR)))
__attribute__((amdgpu_waves_per_eu(1, 1)))
void lstm_ts_kernel(
    const float* __restrict__ x, const float* __restrict__ W0,
    const float* __restrict__ b0, const float* __restrict__ W1,
    const float* __restrict__ b1, const float* __restrict__ Wd,
    const float* __restrict__ bd, float* __restrict__ out)
{
    __shared__ __align__(16) float xbuf[TT];              // 8 KB
    __shared__ __align__(16) float ringP[2][NSLOT][UU];   // private full-h rings, 16 KB
    __shared__ __align__(16) v4f  zpart[2][2][UU];        // [t&1][wid][u], 4 KB
    __shared__ int flagL[2];                              // producer handshake
    __shared__ float red[3];

    const int tid = threadIdx.x;
    const int wid = tid >> 6;
    const int u = tid & 63;
    const int b = blockIdx.x;
    const float* xrow = x + b * TT;
    float* outrow = out + b * TT;

    // ---- prologue: stage x, sum of squares over T (all 3 waves) ----
    float ss = 0.f;
    for (int i = tid; i < TT; i += NTHR) {
        float v = xrow[i];
        xbuf[i] = v;
        ss += v * v;
    }
    #pragma unroll
    for (int m = 1; m < 64; m <<= 1) ss += __shfl_xor(ss, m, 64);
    if (u == 0) red[wid] = ss;
    if (wid < 2) ringP[wid][NSLOT - 1][u] = 0.f;  // h_{-1}=0 (step 0 reads slot 31)
    if (tid < 2) flagL[tid] = 0;
    __syncthreads();  // B0

    if (wid < 2) {
        // ========= PRODUCER wave 'wid': k-half [32*wid, 32*wid+32) =========
        const int koff = 32 * wid;
        const float sq = (red[0] + red[1]) + red[2];
        const float scale = 1.0f / sqrtf(fmaxf(sq, 1e-12f));  // precise, once

        // 64 named v2f = 128 weight VGPRs (identical to r16).
        #define DECLW(k) v2f WI##k, WF##k; { \
            const float* r_ = W0 + (1 + koff + (k)) * 256; \
            WI##k.x = r_[u];       WI##k.y = r_[64 + u]; \
            WF##k.x = r_[128 + u]; WF##k.y = r_[192 + u]; } \
            asm volatile("" : "+v"(WI##k)); asm volatile("" : "+v"(WF##k));
        DECLW(0)  DECLW(1)  DECLW(2)  DECLW(3)  DECLW(4)  DECLW(5)  DECLW(6)  DECLW(7)
        DECLW(8)  DECLW(9)  DECLW(10) DECLW(11) DECLW(12) DECLW(13) DECLW(14) DECLW(15)
        DECLW(16) DECLW(17) DECLW(18) DECLW(19) DECLW(20) DECLW(21) DECLW(22) DECLW(23)
        DECLW(24) DECLW(25) DECLW(26) DECLW(27) DECLW(28) DECLW(29) DECLW(30) DECLW(31)
        #undef DECLW

        // x-row + biases: wave0 only (wave1 chains start at exact 0) -- r16
        const float sel = (wid == 0) ? 1.f : 0.f;
        const float wxi = W0[u] * scale * sel,       wxj = W0[64 + u] * scale * sel;
        const float wxf = W0[128 + u] * scale * sel, wxo = W0[192 + u] * scale * sel;
        const float bci = b0[u] * sel,       bcj = b0[64 + u] * sel;
        const float bcf = b0[128 + u] * sel, bco = b0[192 + u] * sel;

        float c0 = 0.f;

        for (int t = 0; t < TT; ++t) {
            const float xr = xbuf[t];                                   // uniform
            const float* hs = &ringP[wid][(t + NSLOT - 1) & (NSLOT - 1)][koff];

            // 4 chains x 16 deep; x/bias folded into chain 0 (r16 bit-identical)
            v2f ai0, ai1 = 0.f, af0, af1 = 0.f;
            ai0.x = fmaf(xr, wxi, bci); ai0.y = fmaf(xr, wxj, bcj);
            af0.x = fmaf(xr, wxf, bcf); af0.y = fmaf(xr, wxo, bco);

            #define MACR(m, A, B, C, D, E, F, G, H) { \
                v4f hv_ = *(const v4f*)(hs + 4 * (m)); \
                v2f h01_ = __builtin_shufflevector(hv_, hv_, 0, 1); \
                v2f h23_ = __builtin_shufflevector(hv_, hv_, 2, 3); \
                pkfma_ll(ai0, h01_, A); pkfma_ll(af0, h01_, E); \
                pkfma_hh(ai1, h01_, B); pkfma_hh(af1, h01_, F); \
                pkfma_ll(ai0, h23_, C); pkfma_ll(af0, h23_, G); \
                pkfma_hh(ai1, h23_, D); pkfma_hh(af1, h23_, H); \
            }
            MACR(0, WI0,  WI1,  WI2,  WI3,  WF0,  WF1,  WF2,  WF3)
            MACR(1, WI4,  WI5,  WI6,  WI7,  WF4,  WF5,  WF6,  WF7)
            MACR(2, WI8,  WI9,  WI10, WI11, WF8,  WF9,  WF10, WF11)
            MACR(3, WI12, WI13, WI14, WI15, WF12, WF13, WF14, WF15)
            MACR(4, WI16, WI17, WI18, WI19, WF16, WF17, WF18, WF19)
            MACR(5, WI20, WI21, WI22, WI23, WF20, WF21, WF22, WF23)
            MACR(6, WI24, WI25, WI26, WI27, WF24, WF25, WF26, WF27)
            MACR(7, WI28, WI29, WI30, WI31, WF28, WF29, WF30, WF31)
            #undef MACR

            const v2f pij = ai0 + ai1;   // own-half partial (z_i, z_j)
            const v2f pfo = af0 + af1;   // own-half partial (z_f, z_o)
            v4f zp; zp.x = pij.x; zp.y = pij.y; zp.z = pfo.x; zp.w = pfo.y;
            zpart[t & 1][wid][u] = zp;   // ds_write_b128

            // ---- flag handshake (replaces the per-step __syncthreads) ----
            asm volatile("s_waitcnt lgkmcnt(0)" ::: "memory");  // zp committed
            if (u == 0) flagL[wid] = t + 1;
            while (*(volatile int*)&flagL[1 - wid] < t + 1) {}  // uniform poll

            const v4f zo4 = zpart[t & 1][1 - wid][u];  // partner's partial
            const float zi = pij.x + zo4.x;
            const float zj = pij.y + zo4.y;
            const float zf = pfo.x + zo4.z;
            const float zo = pfo.y + zo4.w;

            // unit update -- bit-identical in both producer waves
            c0 = fsigmoid(zf + 1.0f) * c0 + fsigmoid(zi) * ftanh(zj);
            const float h = fsigmoid(zo) * ftanh(c0);

            ringP[wid][t & (NSLOT - 1)][u] = h;   // private full-h ring

            if ((t & (CH - 1)) == (CH - 1)) __syncthreads();  // chunk barrier
        }
    } else {
        // ========== CONSUMER (r17-proven chunk protocol): L1 + dense ==========
        const float w1v0 = W1[u * 4 + 0], w1v1 = W1[u * 4 + 1];
        const float w1v2 = W1[u * 4 + 2], w1v3 = W1[u * 4 + 3];
        const float w1h0 = W1[256], w1h1 = W1[257], w1h2 = W1[258], w1h3 = W1[259];
        const float b10 = b1[0], b11 = b1[1], b12 = b1[2], b13 = b1[3];
        const float wd = Wd[0], bdv = bd[0];

        float c1 = 0.f, h1 = 0.f, oval = 0.f;

        // after barrier k2+1, chunk k2's slots of wave0's ring are complete;
        // wave0 overwrites them only after barrier k2+2 -> race-free.
        for (int k2 = 0; k2 < NCH; ++k2) {
            __syncthreads();
            const int sbase = k2 * CH;
            for (int si = 0; si < CH; ++si) {
                const int s = sbase + si;
                const float hu = ringP[0][s & (NSLOT - 1)][u];  // 4B stride: free
                float p0 = hu * w1v0, p1 = hu * w1v1, p2 = hu * w1v2, p3 = hu * w1v3;
                #pragma unroll
                for (int m = 1; m < 64; m <<= 1) {
                    p0 += __shfl_xor(p0, m, 64);
                    p1 += __shfl_xor(p1, m, 64);
                    p2 += __shfl_xor(p2, m, 64);
                    p3 += __shfl_xor(p3, m, 64);
                }
                const float z1i = p0 + fmaf(h1, w1h0, b10);
                const float z1j = p1 + fmaf(h1, w1h1, b11);
                const float z1f = p2 + fmaf(h1, w1h2, b12);
                const float z1o = p3 + fmaf(h1, w1h3, b13);
                c1 = fsigmoid(z1f + 1.0f) * c1 + fsigmoid(z1i) * ftanh(z1j);
                h1 = fsigmoid(z1o) * ftanh(c1);
                const float ov = fmaf(h1, wd, bdv);
                if ((s & 63) == u) oval = ov;
                if ((s & 63) == 63) outrow[(s & ~63) + u] = oval;
            }
        }
    }
}

extern "C" void kernel_launch(void* const* d_in, const int* in_sizes, int n_in,
                              void* d_out, int out_size, void* d_ws, size_t ws_size,
                              hipStream_t stream) {
    const float* x  = (const float*)d_in[0];
    const float* W0 = (const float*)d_in[1];
    const float* b0 = (const float*)d_in[2];
    const float* W1 = (const float*)d_in[3];
    const float* b1 = (const float*)d_in[4];
    const float* Wd = (const float*)d_in[5];
    const float* bd = (const float*)d_in[6];
    float* out = (float*)d_out;
    lstm_ts_kernel<<<BB, NTHR, 0, stream>>>(x, W0, b0, W1, b1, Wd, bd, out);
}

// Round 19
// 961.111 us; speedup vs baseline: 1.8967x; 1.1273x over previous
//
#include <hip/hip_runtime.h>
#include <math.h>

#define TT 2048
#define UU 64
#define BB 256
#define NTHR 192   // 3 waves: wave0 = k:0..31 (all gates), wave1 = k:32..63, wave2 = consumer

typedef float v2f __attribute__((ext_vector_type(2)));
typedef float v4f __attribute__((ext_vector_type(4)));

// Fast activations on v_exp_f32 / v_rcp_f32 (~1e-7 abs err; threshold 3.45e-6;
// validated across rounds 0-18).
__device__ __forceinline__ float frcp(float x) { return __builtin_amdgcn_rcpf(x); }
__device__ __forceinline__ float fsigmoid(float x) { return frcp(1.0f + __expf(-x)); }
__device__ __forceinline__ float ftanh(float x) { return 1.0f - 2.0f * frcp(1.0f + __expf(2.0f * x)); }

// VOP3P op_sel splat-FMA (r10-validated): both result halves consume the SAME
// 32-bit half of h -- no (h,h) splat is ever materialized.
__device__ __forceinline__ void pkfma_ll(v2f& a, v2f h, v2f w) {
    asm("v_pk_fma_f32 %0, %1, %2, %0 op_sel:[0,0,0] op_sel_hi:[0,1,1]"
        : "+v"(a) : "v"(h), "v"(w));
}
__device__ __forceinline__ void pkfma_hh(v2f& a, v2f h, v2f w) {
    asm("v_pk_fma_f32 %0, %1, %2, %0 op_sel:[1,0,0] op_sel_hi:[1,1,1]"
        : "+v"(a) : "v"(h), "v"(w));
}

// ROUND-18 POST-MORTEM: LDS flag handshake (lgkmcnt(0)+poll ~300cy) is MORE
// expensive than the hardware 3-wave barrier; consumer decoupling bought
// nothing (consumer ~400cy < interval, never the binder). r16 (959us) is the
// verified optimum structure. THIS ROUND: r16 byte-for-byte except ONE
// micro-cut -- MAC accumulation in 8 chains x 8 deep instead of 4 x 16,
// halving the ~80cy serial pkfma tail on the h->z critical path. Final
// reduction gains one 2-level add; summation tree changes (absmax shifts
// slightly, stays ~1e-6). If this is neutral, the per-step serial chain
// (broadcast RT + act chain + exchange + barrier) is the structural floor.
//
// Wave w accumulates h-half k in [32w, 32w+32) for ALL FOUR gates of unit u:
//   8 uniform b128 ring reads + 64 op_sel pkfma -> partial (zi,zj,zf,zo) ->
//   b128 zpart write -> ONE barrier -> partner partial read -> 4 adds ->
//   act (redundant, bit-identical) -> h -> private full-h ring b32 write.
// Wave 2 (consumer): r10/r16-proven 1-step-lag protocol on wave0's ring:
// 4-value 64-lane shuffle reduce + layer-1 LSTM + dense, coalesced flush
// every 64 steps. All 3 waves execute exactly 1 + TT + 1 barriers.
__global__
__attribute__((amdgpu_flat_work_group_size(NTHR, NTHR)))
__attribute__((amdgpu_waves_per_eu(1, 1)))
void lstm_ts_kernel(
    const float* __restrict__ x, const float* __restrict__ W0,
    const float* __restrict__ b0, const float* __restrict__ W1,
    const float* __restrict__ b1, const float* __restrict__ Wd,
    const float* __restrict__ bd, float* __restrict__ out)
{
    __shared__ __align__(16) float xbuf[TT];          // 8 KB
    __shared__ __align__(16) float ringP[2][2][UU];   // private full-h rings, 1 KB
    __shared__ __align__(16) v4f  zpart[2][2][UU];    // [t&1][wid][u] partials, 4 KB
    __shared__ float red[3];

    const int tid = threadIdx.x;
    const int wid = tid >> 6;
    const int u = tid & 63;
    const int b = blockIdx.x;
    const float* xrow = x + b * TT;
    float* outrow = out + b * TT;

    // ---- prologue: stage x, sum of squares over T (all 3 waves) ----
    float ss = 0.f;
    for (int i = tid; i < TT; i += NTHR) {
        float v = xrow[i];
        xbuf[i] = v;
        ss += v * v;
    }
    #pragma unroll
    for (int m = 1; m < 64; m <<= 1) ss += __shfl_xor(ss, m, 64);
    if (u == 0) red[wid] = ss;
    if (wid < 2) ringP[wid][1][u] = 0.f;  // h_{-1}=0: step 0 reads slot 1
    __syncthreads();  // B0

    if (wid < 2) {
        // ========= PRODUCER wave 'wid': k-half [32*wid, 32*wid+32) =========
        const int koff = 32 * wid;
        const float sq = (red[0] + red[1]) + red[2];
        const float scale = 1.0f / sqrtf(fmaxf(sq, 1e-12f));  // precise, once

        // 64 named v2f = 128 weight VGPRs. For local k (global row 1+koff+k):
        // WIk = (Wi[k][u], Wj[k][u]); WFk = (Wf[k][u], Wo[k][u]).
        #define DECLW(k) v2f WI##k, WF##k; { \
            const float* r_ = W0 + (1 + koff + (k)) * 256; \
            WI##k.x = r_[u];       WI##k.y = r_[64 + u]; \
            WF##k.x = r_[128 + u]; WF##k.y = r_[192 + u]; } \
            asm volatile("" : "+v"(WI##k)); asm volatile("" : "+v"(WF##k));
        DECLW(0)  DECLW(1)  DECLW(2)  DECLW(3)  DECLW(4)  DECLW(5)  DECLW(6)  DECLW(7)
        DECLW(8)  DECLW(9)  DECLW(10) DECLW(11) DECLW(12) DECLW(13) DECLW(14) DECLW(15)
        DECLW(16) DECLW(17) DECLW(18) DECLW(19) DECLW(20) DECLW(21) DECLW(22) DECLW(23)
        DECLW(24) DECLW(25) DECLW(26) DECLW(27) DECLW(28) DECLW(29) DECLW(30) DECLW(31)
        #undef DECLW

        // x-row + biases: carried by wave0 only (wave1 chains start at exact 0)
        const float sel = (wid == 0) ? 1.f : 0.f;
        const float wxi = W0[u] * scale * sel,       wxj = W0[64 + u] * scale * sel;
        const float wxf = W0[128 + u] * scale * sel, wxo = W0[192 + u] * scale * sel;
        const float bci = b0[u] * sel,       bcj = b0[64 + u] * sel;
        const float bcf = b0[128 + u] * sel, bco = b0[192 + u] * sel;

        float c0 = 0.f;

        for (int t = 0; t < TT; ++t) {
            const float xr = xbuf[t];                            // uniform
            const float* hs = &ringP[wid][(t + 1) & 1][koff];    // own K-half

            // 8 chains x 8 deep; x/bias folded into chain 0 (wave0)
            v2f ai0, ai1 = 0.f, ai2 = 0.f, ai3 = 0.f;
            v2f af0, af1 = 0.f, af2 = 0.f, af3 = 0.f;
            ai0.x = fmaf(xr, wxi, bci); ai0.y = fmaf(xr, wxj, bcj);
            af0.x = fmaf(xr, wxf, bcf); af0.y = fmaf(xr, wxo, bco);

            // one uniform b128 read = h_{koff+4m..4m+3} -> 8 op_sel pkfma,
            // one per chain (8-deep chains; halves the serial pkfma tail)
            #define MACR(m, A, B, C, D, E, F, G, H) { \
                v4f hv_ = *(const v4f*)(hs + 4 * (m)); \
                v2f h01_ = __builtin_shufflevector(hv_, hv_, 0, 1); \
                v2f h23_ = __builtin_shufflevector(hv_, hv_, 2, 3); \
                pkfma_ll(ai0, h01_, A); pkfma_ll(af0, h01_, E); \
                pkfma_hh(ai1, h01_, B); pkfma_hh(af1, h01_, F); \
                pkfma_ll(ai2, h23_, C); pkfma_ll(af2, h23_, G); \
                pkfma_hh(ai3, h23_, D); pkfma_hh(af3, h23_, H); \
            }
            MACR(0, WI0,  WI1,  WI2,  WI3,  WF0,  WF1,  WF2,  WF3)
            MACR(1, WI4,  WI5,  WI6,  WI7,  WF4,  WF5,  WF6,  WF7)
            MACR(2, WI8,  WI9,  WI10, WI11, WF8,  WF9,  WF10, WF11)
            MACR(3, WI12, WI13, WI14, WI15, WF12, WF13, WF14, WF15)
            MACR(4, WI16, WI17, WI18, WI19, WF16, WF17, WF18, WF19)
            MACR(5, WI20, WI21, WI22, WI23, WF20, WF21, WF22, WF23)
            MACR(6, WI24, WI25, WI26, WI27, WF24, WF25, WF26, WF27)
            MACR(7, WI28, WI29, WI30, WI31, WF28, WF29, WF30, WF31)
            #undef MACR

            const v2f pij = (ai0 + ai1) + (ai2 + ai3);  // own-half (z_i, z_j)
            const v2f pfo = (af0 + af1) + (af2 + af3);  // own-half (z_f, z_o)
            v4f zp; zp.x = pij.x; zp.y = pij.y; zp.z = pfo.x; zp.w = pfo.y;
            zpart[t & 1][wid][u] = zp;   // ds_write_b128
            __syncthreads();             // B(t+1): partials exchanged

            const v4f zo4 = zpart[t & 1][1 - wid][u];  // partner's partial
            const float zi = pij.x + zo4.x;
            const float zj = pij.y + zo4.y;
            const float zf = pfo.x + zo4.z;
            const float zo = pfo.y + zo4.w;

            // unit update -- bit-identical in both producer waves
            c0 = fsigmoid(zf + 1.0f) * c0 + fsigmoid(zi) * ftanh(zj);
            const float h = fsigmoid(zo) * ftanh(c0);

            ringP[wid][t & 1][u] = h;    // private full-h ring, b32 write
        }
        __syncthreads();  // B(TT+1)
    } else {
        // ================= CONSUMER: layer 1 + dense + store =================
        const float w1v0 = W1[u * 4 + 0], w1v1 = W1[u * 4 + 1];
        const float w1v2 = W1[u * 4 + 2], w1v3 = W1[u * 4 + 3];
        const float w1h0 = W1[256], w1h1 = W1[257], w1h2 = W1[258], w1h3 = W1[259];
        const float b10 = b1[0], b11 = b1[1], b12 = b1[2], b13 = b1[3];
        const float wd = Wd[0], bdv = bd[0];

        float c1 = 0.f, h1 = 0.f, oval = 0.f;

        // reads wave0's ring one step lagged: slot s&1 written by wave0 in
        // its post-B(s+1) segment; consumer reads after B(s+2) (requires
        // wave0's arrival -> after the write); slot rewritten only after
        // B(s+3) (requires the consumer's arrival -> after the read).
        #define L1STEP(s) { \
            const float hu = ringP[0][(s) & 1][u];  /* 4B stride: conflict-free */ \
            float p0 = hu * w1v0, p1 = hu * w1v1, p2 = hu * w1v2, p3 = hu * w1v3; \
            _Pragma("unroll") \
            for (int m = 1; m < 64; m <<= 1) { \
                p0 += __shfl_xor(p0, m, 64); \
                p1 += __shfl_xor(p1, m, 64); \
                p2 += __shfl_xor(p2, m, 64); \
                p3 += __shfl_xor(p3, m, 64); \
            } \
            const float z1i = p0 + fmaf(h1, w1h0, b10); \
            const float z1j = p1 + fmaf(h1, w1h1, b11); \
            const float z1f = p2 + fmaf(h1, w1h2, b12); \
            const float z1o = p3 + fmaf(h1, w1h3, b13); \
            c1 = fsigmoid(z1f + 1.0f) * c1 + fsigmoid(z1i) * ftanh(z1j); \
            h1 = fsigmoid(z1o) * ftanh(c1); \
            const float ov = fmaf(h1, wd, bdv); \
            if (((s) & 63) == u) oval = ov; \
            if (((s) & 63) == 63) outrow[((s) & ~63) + u] = oval; \
        }

        for (int t = 0; t < TT; ++t) {
            __syncthreads();  // B(t+1)
            if (t > 0) L1STEP(t - 1)
        }
        __syncthreads();  // B(TT+1) -- makes ring slot (TT-1)&1 visible
        L1STEP(TT - 1)
        #undef L1STEP
    }
}

extern "C" void kernel_launch(void* const* d_in, const int* in_sizes, int n_in,
                              void* d_out, int out_size, void* d_ws, size_t ws_size,
                              hipStream_t stream) {
    const float* x  = (const float*)d_in[0];
    const float* W0 = (const float*)d_in[1];
    const float* b0 = (const float*)d_in[2];
    const float* W1 = (const float*)d_in[3];
    const float* b1 = (const float*)d_in[4];
    const float* Wd = (const float*)d_in[5];
    const float* bd = (const float*)d_in[6];
    float* out = (float*)d_out;
    lstm_ts_kernel<<<BB, NTHR, 0, stream>>>(x, W0, b0, W1, b1, Wd, bd, out);
}